// Round 7
// baseline (278.210 us; speedup 1.0000x reference)
//
#include <hip/hip_runtime.h>

#define TOK 2048
#define DDIM 1024
#define HDIM 1408
#define ENUM 8
#define NSLOT (2 * TOK)
#define UP_NB 11   // HDIM / 128
#define UP_KS 32   // DDIM / 32
#define DN_NB 8    // DDIM / 128
#define DN_KS 44   // HDIM / 32

typedef unsigned int uint;
typedef unsigned short ushort;

using bf16x8 = __attribute__((ext_vector_type(8))) __bf16;
using f32x4  = __attribute__((ext_vector_type(4))) float;

__device__ __forceinline__ float silu_f(float g) {
    return g / (1.0f + __expf(-g));
}

__device__ __forceinline__ ushort cvt_bf16(float f) {
    uint u = __float_as_uint(f);
    u += 0x7FFFu + ((u >> 16) & 1u);   // RNE
    return (ushort)(u >> 16);
}

// async global->LDS: per-lane global address, LDS dest = wave-uniform base + lane*16
__device__ __forceinline__ void gl2lds16(const void* g, void* l) {
    __builtin_amdgcn_global_load_lds(
        (const __attribute__((address_space(1))) uint*)g,
        (__attribute__((address_space(3))) uint*)l, 16, 0, 0);
}

// ---- gate1: one wave/token; top-2 + weights; NO atomics; emits bf16 x ----
__global__ __launch_bounds__(64) void gate1_kernel(
    const float* __restrict__ x, const float* __restrict__ gw,
    int* __restrict__ tinfo, float* __restrict__ wslot, ushort* __restrict__ xb)
{
    const int t = blockIdx.x;
    const int lane = threadIdx.x;
    const float* xr = x + (size_t)t * DDIM;
    ushort* xbr = xb + (size_t)t * DDIM;
    float xv[16];
#pragma unroll
    for (int i = 0; i < 16; ++i) xv[i] = xr[lane + 64 * i];
#pragma unroll
    for (int i = 0; i < 16; ++i) xbr[lane + 64 * i] = cvt_bf16(xv[i]);
    float logit[ENUM];
#pragma unroll
    for (int e = 0; e < ENUM; ++e) {
        const float* gr = gw + (size_t)e * DDIM;
        float acc = 0.f;
#pragma unroll
        for (int i = 0; i < 16; ++i) acc += xv[i] * gr[lane + 64 * i];
#pragma unroll
        for (int s = 32; s > 0; s >>= 1) acc += __shfl_xor(acc, s, 64);
        logit[e] = acc;
    }
    if (lane == 0) {
        float mx = logit[0];
#pragma unroll
        for (int e = 1; e < ENUM; ++e) mx = fmaxf(mx, logit[e]);
        float p[ENUM]; float se = 0.f;
#pragma unroll
        for (int e = 0; e < ENUM; ++e) { p[e] = __expf(logit[e] - mx); se += p[e]; }
        float inv = 1.0f / se;
#pragma unroll
        for (int e = 0; e < ENUM; ++e) p[e] *= inv;
        int i0 = 0;
#pragma unroll
        for (int e = 1; e < ENUM; ++e) if (p[e] > p[i0]) i0 = e;
        int i1 = (i0 == 0) ? 1 : 0;
#pragma unroll
        for (int e = 0; e < ENUM; ++e) if (e != i0 && p[e] > p[i1]) i1 = e;
        tinfo[t] = i0 | (i1 << 4);
        wslot[(t << 1)] = p[i0];
        wslot[(t << 1) | 1] = p[i1];
    }
}

// ---- gate2: single block builds all expert lists with LDS atomics --------
__global__ __launch_bounds__(256) void gate2_kernel(
    const int* __restrict__ tinfo, int* __restrict__ counts, int* __restrict__ toks)
{
    __shared__ int cnt[ENUM];
    const int tid = threadIdx.x;
    if (tid < ENUM) cnt[tid] = 0;
    __syncthreads();
    for (int t = tid; t < TOK; t += 256) {
        int info = tinfo[t];
        int i0 = info & 15, i1 = info >> 4;
        int p0 = atomicAdd(&cnt[i0], 1);
        toks[i0 * TOK + p0] = (t << 1);
        int p1 = atomicAdd(&cnt[i1], 1);
        toks[i1 * TOK + p1] = (t << 1) | 1;
    }
    __syncthreads();
    if (tid < ENUM) counts[tid] = cnt[tid];
}

// ---- tcast128 body: fp32 [K][N] slab -> bf16 tiles [ks][nn(128)][kk(32)] --
__device__ __forceinline__ void tcast128_body(
    const float* __restrict__ src, ushort* __restrict__ dst, int N, int KS, int NB,
    int e, int ks, int nb, int tid)
{
    __shared__ float Ls[32][132];
    const float* st = src + (size_t)e * ((size_t)KS * 32) * N + (size_t)(ks * 32) * N + nb * 128;
    const int n4 = (tid & 31) * 4;
#pragma unroll
    for (int r = 0; r < 4; ++r) {
        int k = (tid >> 5) + r * 8;
        float4 v = *(const float4*)(st + (size_t)k * N + n4);
        Ls[k][n4 + 0] = v.x; Ls[k][n4 + 1] = v.y; Ls[k][n4 + 2] = v.z; Ls[k][n4 + 3] = v.w;
    }
    __syncthreads();

    ushort* dt = dst + ((((size_t)e * NB + nb) * KS) + ks) * 4096;
    const int nn = tid >> 1;
    const int kk0 = (tid & 1) * 16;
    ushort o[16];
#pragma unroll
    for (int j = 0; j < 16; ++j) o[j] = cvt_bf16(Ls[kk0 + j][nn]);
    *(uint4*)(dt + nn * 32 + kk0)     = *(uint4*)&o[0];
    *(uint4*)(dt + nn * 32 + kk0 + 8) = *(uint4*)&o[8];
}

// w1g + w1u fused (z = 0..15: low 3 bits expert, bit 3 selects tensor)
__global__ __launch_bounds__(256) void tcast_w1_kernel(
    const float* __restrict__ w1g, const float* __restrict__ w1u,
    ushort* __restrict__ BgP, ushort* __restrict__ BuP)
{
    const int z = blockIdx.z;
    const float* src = (z & 8) ? w1u : w1g;
    ushort* dst = (z & 8) ? BuP : BgP;
    tcast128_body(src, dst, HDIM, UP_KS, UP_NB, z & 7, blockIdx.x, blockIdx.y, threadIdx.x);
}

__global__ __launch_bounds__(256) void tcast_w2_kernel(
    const float* __restrict__ w2, ushort* __restrict__ W2P)
{
    tcast128_body(w2, W2P, DDIM, DN_KS, DN_NB, blockIdx.z, blockIdx.x, blockIdx.y, threadIdx.x);
}

// ---- up: Hbuf[slot] = silu(x@w1g[e]) * (x@w1u[e]); TM=128 TN=128, dbuf,
//      XOR-swizzled LDS (phys16Bchunk = (logical + (row>>1)) & 3) ----------
__global__ __launch_bounds__(256, 2) void up_mfma(
    const ushort* __restrict__ xb, const ushort* __restrict__ BgP,
    const ushort* __restrict__ BuP, const int* __restrict__ counts,
    const int* __restrict__ toks, ushort* __restrict__ Hbuf)
{
    const int e = blockIdx.z;
    const int cnt = counts[e];
    const int m0 = blockIdx.y * 128;
    if (m0 >= cnt) return;
    const int nb = blockIdx.x;
    const int tid = threadIdx.x;
    const int w = tid >> 6;
    const int lane = tid & 63;
    const int q = lane >> 4;
    const int l15 = lane & 15;
    const int wr = w >> 1;   // 2x2 wave grid: wave tile 64m x 64n
    const int wc = w & 1;

    __shared__ ushort As[2][128][32];
    __shared__ ushort Bgs[2][128][32];
    __shared__ ushort Bus[2][128][32];
    __shared__ int rowslot[128];

    if (tid < 128) rowslot[tid] = (m0 + tid < cnt) ? toks[e * TOK + m0 + tid] : -1;
    __syncthreads();

    // staging: wave w stages rows [w*32, w*32+32) of each tile (2 x 16-row groups)
    // within a group: row = g*16 + (lane>>2), phys chunk = lane&3
    // logical chunk for swizzle: (phys - (row>>1)) & 3  (same for both groups: +16 rows -> +8 ≡ 0 mod 4)
    const int srow0 = w * 32 + (lane >> 2);
    const int srow1 = srow0 + 16;
    const int clog = (((lane & 3) + 4 - ((srow0 >> 1) & 3)) & 3) * 8;
    const int s0 = rowslot[srow0];
    const int s1 = rowslot[srow1];
    const ushort* agp0 = xb + (size_t)(s0 < 0 ? 0 : (s0 >> 1)) * DDIM + clog;
    const ushort* agp1 = xb + (size_t)(s1 < 0 ? 0 : (s1 >> 1)) * DDIM + clog;
    const size_t tb = (size_t)(e * UP_NB + nb) * UP_KS * 4096;
    const ushort* bgp = BgP + tb + srow0 * 32 + clog;
    const ushort* bup = BuP + tb + srow0 * 32 + clog;

    // reads: lane-constant swizzled chunk offset
    const int coff = ((q + (l15 >> 1)) & 3) * 8;

    f32x4 accg[4][4], accu[4][4];
#pragma unroll
    for (int i = 0; i < 4; ++i)
#pragma unroll
        for (int j = 0; j < 4; ++j) { accg[i][j] = (f32x4)0.f; accu[i][j] = (f32x4)0.f; }

#define UP_PREFETCH(KSV, B)                                                 \
    {                                                                       \
        gl2lds16(agp0 + (KSV) * 32, &As[B][w * 32][0]);                     \
        gl2lds16(agp1 + (KSV) * 32, &As[B][w * 32 + 16][0]);                \
        gl2lds16(bgp + (size_t)(KSV) * 4096, &Bgs[B][w * 32][0]);           \
        gl2lds16(bgp + (size_t)(KSV) * 4096 + 512, &Bgs[B][w * 32 + 16][0]);\
        gl2lds16(bup + (size_t)(KSV) * 4096, &Bus[B][w * 32][0]);           \
        gl2lds16(bup + (size_t)(KSV) * 4096 + 512, &Bus[B][w * 32 + 16][0]);\
    }

    UP_PREFETCH(0, 0);
    __syncthreads();

    for (int ks = 0; ks < UP_KS; ++ks) {
        const int cur = ks & 1;
        const int nxt = cur ^ 1;
        if (ks + 1 < UP_KS) UP_PREFETCH(ks + 1, nxt);

        bf16x8 a[4], bg[4], bu[4];
#pragma unroll
        for (int mi = 0; mi < 4; ++mi)
            a[mi] = *(const bf16x8*)&As[cur][wr * 64 + mi * 16 + l15][coff];
#pragma unroll
        for (int ni = 0; ni < 4; ++ni) {
            bg[ni] = *(const bf16x8*)&Bgs[cur][wc * 64 + ni * 16 + l15][coff];
            bu[ni] = *(const bf16x8*)&Bus[cur][wc * 64 + ni * 16 + l15][coff];
        }
#pragma unroll
        for (int mi = 0; mi < 4; ++mi)
#pragma unroll
            for (int ni = 0; ni < 4; ++ni) {
                accg[mi][ni] = __builtin_amdgcn_mfma_f32_16x16x32_bf16(a[mi], bg[ni], accg[mi][ni], 0, 0, 0);
                accu[mi][ni] = __builtin_amdgcn_mfma_f32_16x16x32_bf16(a[mi], bu[ni], accu[mi][ni], 0, 0, 0);
            }
        __syncthreads();   // drains prefetch vmem + protects buffer swap
    }
#undef UP_PREFETCH

#pragma unroll
    for (int mi = 0; mi < 4; ++mi) {
#pragma unroll
        for (int r = 0; r < 4; ++r) {
            int ml = wr * 64 + mi * 16 + q * 4 + r;
            int slot = rowslot[ml];
            if (slot < 0) continue;
            ushort* hrow = Hbuf + (size_t)slot * HDIM + nb * 128 + wc * 64 + l15;
#pragma unroll
            for (int ni = 0; ni < 4; ++ni)
                hrow[ni * 16] = cvt_bf16(silu_f(accg[mi][ni][r]) * accu[mi][ni][r]);
        }
    }
}

// ---- down: Ybuf[slot] = Hbuf[slot] @ w2[e]; TM=128 TN=128, dbuf, swizzled -
__global__ __launch_bounds__(256, 2) void down_mfma(
    const ushort* __restrict__ Hbuf, const ushort* __restrict__ W2P,
    const int* __restrict__ counts, const int* __restrict__ toks,
    float* __restrict__ Ybuf)
{
    const int e = blockIdx.z;
    const int cnt = counts[e];
    const int m0 = blockIdx.y * 128;
    if (m0 >= cnt) return;
    const int nb = blockIdx.x;
    const int tid = threadIdx.x;
    const int w = tid >> 6;
    const int lane = tid & 63;
    const int q = lane >> 4;
    const int l15 = lane & 15;
    const int wr = w >> 1;
    const int wc = w & 1;

    __shared__ ushort As[2][128][32];
    __shared__ ushort Bs[2][128][32];
    __shared__ int rowslot[128];

    if (tid < 128) rowslot[tid] = (m0 + tid < cnt) ? toks[e * TOK + m0 + tid] : -1;
    __syncthreads();

    const int srow0 = w * 32 + (lane >> 2);
    const int srow1 = srow0 + 16;
    const int clog = (((lane & 3) + 4 - ((srow0 >> 1) & 3)) & 3) * 8;
    const int s0 = rowslot[srow0];
    const int s1 = rowslot[srow1];
    const ushort* agp0 = Hbuf + (size_t)(s0 < 0 ? 0 : s0) * HDIM + clog;
    const ushort* agp1 = Hbuf + (size_t)(s1 < 0 ? 0 : s1) * HDIM + clog;
    const ushort* bp = W2P + (size_t)(e * DN_NB + nb) * DN_KS * 4096 + srow0 * 32 + clog;

    const int coff = ((q + (l15 >> 1)) & 3) * 8;

    f32x4 acc[4][4];
#pragma unroll
    for (int i = 0; i < 4; ++i)
#pragma unroll
        for (int j = 0; j < 4; ++j) acc[i][j] = (f32x4)0.f;

#define DN_PREFETCH(KSV, B)                                               \
    {                                                                     \
        gl2lds16(agp0 + (KSV) * 32, &As[B][w * 32][0]);                   \
        gl2lds16(agp1 + (KSV) * 32, &As[B][w * 32 + 16][0]);              \
        gl2lds16(bp + (size_t)(KSV) * 4096, &Bs[B][w * 32][0]);           \
        gl2lds16(bp + (size_t)(KSV) * 4096 + 512, &Bs[B][w * 32 + 16][0]);\
    }

    DN_PREFETCH(0, 0);
    __syncthreads();

    for (int ks = 0; ks < DN_KS; ++ks) {
        const int cur = ks & 1;
        const int nxt = cur ^ 1;
        if (ks + 1 < DN_KS) DN_PREFETCH(ks + 1, nxt);

        bf16x8 a[4], b[4];
#pragma unroll
        for (int mi = 0; mi < 4; ++mi)
            a[mi] = *(const bf16x8*)&As[cur][wr * 64 + mi * 16 + l15][coff];
#pragma unroll
        for (int ni = 0; ni < 4; ++ni)
            b[ni] = *(const bf16x8*)&Bs[cur][wc * 64 + ni * 16 + l15][coff];
#pragma unroll
        for (int mi = 0; mi < 4; ++mi)
#pragma unroll
            for (int ni = 0; ni < 4; ++ni)
                acc[mi][ni] = __builtin_amdgcn_mfma_f32_16x16x32_bf16(a[mi], b[ni], acc[mi][ni], 0, 0, 0);
        __syncthreads();
    }
#undef DN_PREFETCH

#pragma unroll
    for (int mi = 0; mi < 4; ++mi) {
#pragma unroll
        for (int r = 0; r < 4; ++r) {
            int ml = wr * 64 + mi * 16 + q * 4 + r;
            int slot = rowslot[ml];
            if (slot < 0) continue;
            float* yr = Ybuf + (size_t)slot * DDIM + nb * 128 + wc * 64 + l15;
#pragma unroll
            for (int ni = 0; ni < 4; ++ni)
                yr[ni * 16] = acc[mi][ni][r];
        }
    }
}

// ---- combine: y[t] = w0*Ybuf[2t] + w1*Ybuf[2t+1] -------------------------
__global__ __launch_bounds__(256) void combine_kernel(
    const float* __restrict__ Ybuf, const float* __restrict__ wslot,
    float* __restrict__ y)
{
    const int t = blockIdx.x;
    const int j = threadIdx.x * 4;
    const float w0 = wslot[2 * t];
    const float w1 = wslot[2 * t + 1];
    float4 a = *(const float4*)(Ybuf + ((size_t)2 * t) * DDIM + j);
    float4 b = *(const float4*)(Ybuf + ((size_t)2 * t + 1) * DDIM + j);
    float4 o;
    o.x = w0 * a.x + w1 * b.x;
    o.y = w0 * a.y + w1 * b.y;
    o.z = w0 * a.z + w1 * b.z;
    o.w = w0 * a.w + w1 * b.w;
    *(float4*)(y + (size_t)t * DDIM + j) = o;
}

extern "C" void kernel_launch(void* const* d_in, const int* in_sizes, int n_in,
                              void* d_out, int out_size, void* d_ws, size_t ws_size,
                              hipStream_t stream) {
    const float* x   = (const float*)d_in[0];
    const float* gw  = (const float*)d_in[1];
    const float* w1g = (const float*)d_in[2];
    const float* w1u = (const float*)d_in[3];
    const float* w2  = (const float*)d_in[4];
    float* y = (float*)d_out;
    char* ws = (char*)d_ws;

    // workspace layout (Ybuf aliases BgP/BuP region — dead after up_mfma)
    size_t off = 0;
    int*    counts = (int*)(ws + off);   off += 256;
    int*    toks   = (int*)(ws + off);   off += (size_t)ENUM * TOK * 4;   // 64 KB
    float*  wslot  = (float*)(ws + off); off += (size_t)NSLOT * 4;        // 16 KB
    int*    tinfo  = (int*)(ws + off);   off += (size_t)TOK * 4;          // 8 KB
    off = (off + 255) & ~(size_t)255;
    ushort* xb     = (ushort*)(ws + off); off += (size_t)TOK * DDIM * 2;  // 4 MB
    size_t regA = off;                                                    // 46 MB region
    ushort* BgP  = (ushort*)(ws + regA);
    ushort* BuP  = (ushort*)(ws + regA + (size_t)ENUM * DDIM * HDIM * 2);
    float*  Ybuf = (float*)(ws + regA);                                   // 16.8 MB alias
    off = regA + (size_t)2 * ENUM * DDIM * HDIM * 2;
    ushort* W2P  = (ushort*)(ws + off);  off += (size_t)ENUM * HDIM * DDIM * 2; // 23 MB
    ushort* Hbuf = (ushort*)(ws + off);                                         // 11.5 MB

    gate1_kernel<<<TOK, 64, 0, stream>>>(x, gw, tinfo, wslot, xb);
    gate2_kernel<<<1, 256, 0, stream>>>(tinfo, counts, toks);

    tcast_w1_kernel<<<dim3(UP_KS, UP_NB, 16), 256, 0, stream>>>(w1g, w1u, BgP, BuP);
    tcast_w2_kernel<<<dim3(DN_KS, DN_NB, ENUM), 256, 0, stream>>>(w2, W2P);

    up_mfma<<<dim3(UP_NB, TOK / 128, ENUM), 256, 0, stream>>>(xb, BgP, BuP, counts, toks, Hbuf);
    down_mfma<<<dim3(DN_NB, TOK / 128, ENUM), 256, 0, stream>>>(Hbuf, W2P, counts, toks, Ybuf);
    combine_kernel<<<TOK, 256, 0, stream>>>(Ybuf, wslot, y);
}